// Round 6
// baseline (149.403 us; speedup 1.0000x reference)
//
#include <hip/hip_runtime.h>
#include <hip/hip_bf16.h>

#define B_  64
#define T_  2048
#define E_  512
#define Q_  1024
#define A_  128
#define C_  32
#define KW_ 31

using bf16x8 = __attribute__((ext_vector_type(8))) short;
using f32x4  = __attribute__((ext_vector_type(4))) float;

__device__ __forceinline__ short f2bf(float f) {
  union { float f; unsigned u; } x; x.f = f;
  unsigned r = x.u + 0x7fffu + ((x.u >> 16) & 1u);   // RNE
  return (short)(r >> 16);
}

__device__ __forceinline__ bf16x8 pack8(float4 a, float4 b) {
  union { bf16x8 v; __hip_bfloat162 h[4]; } u;
  u.h[0] = __float22bfloat162_rn(make_float2(a.x, a.y));
  u.h[1] = __float22bfloat162_rn(make_float2(a.z, a.w));
  u.h[2] = __float22bfloat162_rn(make_float2(b.x, b.y));
  u.h[3] = __float22bfloat162_rn(make_float2(b.z, b.w));
  return u.v;
}

__device__ __forceinline__ float fast_tanh(float x) {
  float e2 = __expf(2.f * x);
  return 1.f - 2.f * __builtin_amdgcn_rcpf(e2 + 1.f);
}

__device__ __forceinline__ void gload16(const void* g, void* l) {
  __builtin_amdgcn_global_load_lds(
      (const __attribute__((address_space(1))) unsigned int*)g,
      (__attribute__((address_space(3))) unsigned int*)l, 16, 0, 0);
}

// ---------------- prep: q2 partials (b x 8 K-slices); Wk,Wloc -> MFMA B-frag order (bf16)
__global__ __launch_bounds__(256) void prep_kernel(
    const float* __restrict__ dh, const float* __restrict__ Wq,
    const float* __restrict__ conv_b, const float* __restrict__ Wloc,
    const float* __restrict__ Wk,
    unsigned short* __restrict__ wkf, unsigned short* __restrict__ wlocf,
    float* __restrict__ q2p)
{
  int blk = blockIdx.x;
  int tid = threadIdx.x;
  if (blk < 512) {
    __shared__ float part[128];
    int b = blk >> 3, kq = blk & 7;
    int a = tid & 127, kh = tid >> 7;
    const float* dhr = dh + b * Q_ + kq * 128 + kh * 64;
    const float* wq  = Wq + (size_t)(kq * 128 + kh * 64) * A_ + a;
    float s = 0.f;
    #pragma unroll 8
    for (int k = 0; k < 64; ++k) s += dhr[k] * wq[(size_t)k * A_];
    if (kh) part[a] = s;
    __syncthreads();
    if (!kh) {
      s += part[a];
      if (kq == 0) {
        float t = 0.f;
        #pragma unroll 8
        for (int c = 0; c < C_; ++c) t += conv_b[c] * Wloc[c * A_ + a];
        s += t;
      }
      q2p[(kq * B_ + b) * A_ + a] = s;
    }
  } else if (blk < 544) {
    int wave = tid >> 6, lane = tid & 63;
    int g = (blk - 512) * 4 + wave;          // 0..127
    int ks = g >> 3, nt = g & 7;
    int lg = lane >> 4, lr = lane & 15;
    bf16x8 o;
    #pragma unroll
    for (int j = 0; j < 8; ++j)
      o[j] = f2bf(Wk[(ks * 32 + lg * 8 + j) * A_ + nt * 16 + lr]);
    *(bf16x8*)(wkf + ((size_t)g * 64 + lane) * 8) = o;
  } else {
    int wave = tid >> 6, lane = tid & 63;
    int g = (blk - 544) * 4 + wave;          // 0..7
    int lg = lane >> 4, lr = lane & 15;
    bf16x8 o;
    #pragma unroll
    for (int j = 0; j < 8; ++j)
      o[j] = f2bf(Wloc[(lg * 8 + j) * A_ + g * 16 + lr]);
    *(bf16x8*)(wlocf + ((size_t)g * 64 + lane) * 8) = o;
  }
}

// ---------------- energy: ALL 17 B-slices resident in LDS (136 KB), zero barriers
// in the K-loop. 512 blocks x 512 threads (8 waves, 32 rows each = 256 rows/block).
__global__ __launch_bounds__(512) void energy_kernel(
    const float* __restrict__ enc, const float* __restrict__ prev,
    const float* __restrict__ conv_w,
    const unsigned short* __restrict__ wkfall,   // slices 0..15 = Wk, 16 = Wloc
    const float* __restrict__ q2p, const float* __restrict__ vvec,
    float* __restrict__ outexp, float* __restrict__ psum)
{
  __shared__ unsigned short sWB[69632];   // 17 * 4096 shorts = 136 KB
  __shared__ float sprev[288];            // 256 + 30 halo
  __shared__ float scw[KW_][C_];
  __shared__ float swsum[8];

  int tid = threadIdx.x;
  int wave = tid >> 6, lane = tid & 63;
  int lg = lane >> 4, lr = lane & 15;
  int m0 = blockIdx.x * 256;              // flattened b*T + t base of this block
  int b  = m0 >> 11, t0 = m0 & (T_ - 1);
  int wm = m0 + wave * 32;                // this wave's 32 rows

  // (1) conv inputs -> LDS (these vmem loads are OLDEST)
  for (int i = tid; i < 286; i += 512) {
    int t = t0 - 15 + i;
    sprev[i] = (t >= 0 && t < T_) ? prev[b * T_ + t] : 0.f;
  }
  for (int i = tid; i < KW_ * C_; i += 512)
    scw[i >> 5][i & 31] = conv_w[(i & 31) * KW_ + (i >> 5)];

  // (2) stage ALL B slices: 17 x 8 KB, each wave 1 KB per slice (linear dest)
  #pragma unroll
  for (int s = 0; s < 17; ++s)
    gload16(wkfall + (size_t)s * 4096 + wave * 512 + lane * 8,
            &sWB[s * 4096 + wave * 512]);

  // (3) A-prefetch for ks=0 (overlaps staging + conv)
  const float* encR0 = enc + (size_t)(wm + lr) * E_ + lg * 8;
  const float* encR1 = encR0 + 16 * E_;
  float4 n0 = *(const float4*)(encR0), n1 = *(const float4*)(encR0 + 4);
  float4 n2 = *(const float4*)(encR1), n3 = *(const float4*)(encR1 + 4);

  // (4) conv (registers only): lane owns rows (wave*32+lr, +16), ch lg*8..+8
  asm volatile("s_waitcnt lgkmcnt(0)" ::: "memory");   // sprev/scw ds_writes visible
  __builtin_amdgcn_s_barrier();
  __builtin_amdgcn_sched_barrier(0);
  float c0[8], c1[8];
  #pragma unroll
  for (int c = 0; c < 8; ++c) { c0[c] = 0.f; c1[c] = 0.f; }
  {
    int r0 = wave * 32 + lr, r1 = r0 + 16;
    for (int j = 0; j < KW_; ++j) {
      float p0 = sprev[r0 + j], p1 = sprev[r1 + j];
      float4 wA = *(const float4*)&scw[j][lg * 8];
      float4 wB = *(const float4*)&scw[j][lg * 8 + 4];
      c0[0] += p0 * wA.x; c0[1] += p0 * wA.y; c0[2] += p0 * wA.z; c0[3] += p0 * wA.w;
      c0[4] += p0 * wB.x; c0[5] += p0 * wB.y; c0[6] += p0 * wB.z; c0[7] += p0 * wB.w;
      c1[0] += p1 * wA.x; c1[1] += p1 * wA.y; c1[2] += p1 * wA.z; c1[3] += p1 * wA.w;
      c1[4] += p1 * wB.x; c1[5] += p1 * wB.y; c1[6] += p1 * wB.z; c1[7] += p1 * wB.w;
    }
  }
  bf16x8 afl0 = pack8(make_float4(c0[0], c0[1], c0[2], c0[3]),
                      make_float4(c0[4], c0[5], c0[6], c0[7]));
  bf16x8 afl1 = pack8(make_float4(c1[0], c1[1], c1[2], c1[3]),
                      make_float4(c1[4], c1[5], c1[6], c1[7]));

  // (5) B staging complete for ALL waves
  asm volatile("s_waitcnt vmcnt(0)" ::: "memory");
  __builtin_amdgcn_s_barrier();
  __builtin_amdgcn_sched_barrier(0);

  // (6) K-loop: no barriers, no explicit waits — compiler-scheduled
  f32x4 acc0[8], acc1[8];
  #pragma unroll
  for (int i = 0; i < 8; ++i) { acc0[i] = (f32x4){0,0,0,0}; acc1[i] = (f32x4){0,0,0,0}; }

  #pragma unroll 1
  for (int ks = 0; ks < 16; ++ks) {
    float4 u0 = n0, u1 = n1, u2 = n2, u3 = n3;
    if (ks < 15) {
      const float* r0 = encR0 + (ks + 1) * 32;
      const float* r1 = encR1 + (ks + 1) * 32;
      n0 = *(const float4*)(r0); n1 = *(const float4*)(r0 + 4);
      n2 = *(const float4*)(r1); n3 = *(const float4*)(r1 + 4);
    }
    bf16x8 af0 = pack8(u0, u1), af1 = pack8(u2, u3);
    const unsigned short* base = &sWB[ks * 4096 + lane * 8];
    #pragma unroll
    for (int nt = 0; nt < 8; ++nt) {
      bf16x8 bfr = *(const bf16x8*)(base + nt * 512);
      acc0[nt] = __builtin_amdgcn_mfma_f32_16x16x32_bf16(af0, bfr, acc0[nt], 0, 0, 0);
      acc1[nt] = __builtin_amdgcn_mfma_f32_16x16x32_bf16(af1, bfr, acc1[nt], 0, 0, 0);
    }
  }
  { // location term: slice 16, A = conv regs
    const unsigned short* base = &sWB[16 * 4096 + lane * 8];
    #pragma unroll
    for (int nt = 0; nt < 8; ++nt) {
      bf16x8 bfr = *(const bf16x8*)(base + nt * 512);
      acc0[nt] = __builtin_amdgcn_mfma_f32_16x16x32_bf16(afl0, bfr, acc0[nt], 0, 0, 0);
      acc1[nt] = __builtin_amdgcn_mfma_f32_16x16x32_bf16(afl1, bfr, acc1[nt], 0, 0, 0);
    }
  }

  // (7) epilogue: qv = sum of 8 q2 partials; p = v.tanh(acc+qv); out = exp(p)
  float qv[8], vv[8];
  #pragma unroll
  for (int nt = 0; nt < 8; ++nt) {
    int n = nt * 16 + lr;
    float s = 0.f;
    #pragma unroll
    for (int p = 0; p < 8; ++p) s += q2p[(p * B_ + b) * A_ + n];
    qv[nt] = s;
    vv[nt] = vvec[n];
  }
  float ssum = 0.f;
  #pragma unroll
  for (int f = 0; f < 2; ++f) {
    f32x4* acc = f ? acc1 : acc0;
    float p0 = 0, p1 = 0, p2 = 0, p3 = 0;
    #pragma unroll
    for (int nt = 0; nt < 8; ++nt) {
      p0 += fast_tanh(acc[nt][0] + qv[nt]) * vv[nt];
      p1 += fast_tanh(acc[nt][1] + qv[nt]) * vv[nt];
      p2 += fast_tanh(acc[nt][2] + qv[nt]) * vv[nt];
      p3 += fast_tanh(acc[nt][3] + qv[nt]) * vv[nt];
    }
    #pragma unroll
    for (int off = 1; off < 16; off <<= 1) {
      p0 += __shfl_xor(p0, off, 64);
      p1 += __shfl_xor(p1, off, 64);
      p2 += __shfl_xor(p2, off, 64);
      p3 += __shfl_xor(p3, off, 64);
    }
    float e0 = __expf(p0), e1 = __expf(p1), e2 = __expf(p2), e3 = __expf(p3);
    ssum += (e0 + e1) + (e2 + e3);
    if (lr == 0)
      *(float4*)(outexp + wm + f * 16 + lg * 4) = make_float4(e0, e1, e2, e3);
  }
  ssum += __shfl_xor(ssum, 16, 64);
  ssum += __shfl_xor(ssum, 32, 64);
  if (lane == 0) swsum[wave] = ssum;
  __syncthreads();
  if (tid == 0) {
    float s = 0.f;
    #pragma unroll
    for (int wv = 0; wv < 8; ++wv) s += swsum[wv];
    psum[b * 8 + (blockIdx.x & 7)] = s;
  }
}

// ---------------- normalize: out[b,:] *= 1/sum(psum[b,:])
__global__ __launch_bounds__(256) void norm_kernel(float* __restrict__ out,
                                                   const float* __restrict__ psum)
{
  int b = blockIdx.x, tid = threadIdx.x;
  float s = 0.f;
  #pragma unroll
  for (int p = 0; p < 8; ++p) s += psum[b * 8 + p];
  float inv = 1.f / s;
  float4* row = (float4*)(out + (size_t)b * T_);
  #pragma unroll
  for (int j = 0; j < 2; ++j) {
    float4 x = row[tid + j * 256];
    x.x *= inv; x.y *= inv; x.z *= inv; x.w *= inv;
    row[tid + j * 256] = x;
  }
}

extern "C" void kernel_launch(void* const* d_in, const int* in_sizes, int n_in,
                              void* d_out, int out_size, void* d_ws, size_t ws_size,
                              hipStream_t stream)
{
  const float* enc   = (const float*)d_in[0];
  const float* dh    = (const float*)d_in[1];
  const float* prev  = (const float*)d_in[2];
  const float* Wq    = (const float*)d_in[3];
  const float* Wk    = (const float*)d_in[4];
  const float* convw = (const float*)d_in[5];
  const float* convb = (const float*)d_in[6];
  const float* Wloc  = (const float*)d_in[7];
  const float* v     = (const float*)d_in[8];
  float* out = (float*)d_out;

  char* w = (char*)d_ws;
  unsigned short* wkf   = (unsigned short*)w;               // slices 0..15, 131072 B
  unsigned short* wlocf = (unsigned short*)(w + 131072);    // slice 16, 8192 B (contiguous)
  float*          q2p   = (float*)(w + 139264);             // 8*64*128 f32 = 262144 B
  float*          psum  = (float*)(w + 401408);             // 64*8 f32 = 2048 B

  hipLaunchKernelGGL(prep_kernel, dim3(546), dim3(256), 0, stream,
                     dh, Wq, convb, Wloc, Wk, wkf, wlocf, q2p);
  hipLaunchKernelGGL(energy_kernel, dim3(512), dim3(512), 0, stream,
                     enc, prev, convw, wkf, q2p, v, out, psum);
  hipLaunchKernelGGL(norm_kernel, dim3(64), dim3(256), 0, stream, out, psum);
}

// Round 7
// 68.755 us; speedup vs baseline: 2.1730x; 2.1730x over previous
//
#include <hip/hip_runtime.h>
#include <hip/hip_bf16.h>

#define B_  64
#define T_  2048
#define E_  512
#define Q_  1024
#define A_  128
#define C_  32
#define KW_ 31

using bf16x8 = __attribute__((ext_vector_type(8))) short;
using f32x4  = __attribute__((ext_vector_type(4))) float;

__device__ __forceinline__ short f2bf(float f) {
  union { float f; unsigned u; } x; x.f = f;
  unsigned r = x.u + 0x7fffu + ((x.u >> 16) & 1u);   // RNE
  return (short)(r >> 16);
}

__device__ __forceinline__ bf16x8 pack8(float4 a, float4 b) {
  union { bf16x8 v; __hip_bfloat162 h[4]; } u;
  u.h[0] = __float22bfloat162_rn(make_float2(a.x, a.y));
  u.h[1] = __float22bfloat162_rn(make_float2(a.z, a.w));
  u.h[2] = __float22bfloat162_rn(make_float2(b.x, b.y));
  u.h[3] = __float22bfloat162_rn(make_float2(b.z, b.w));
  return u.v;
}

__device__ __forceinline__ float fast_tanh(float x) {
  float e2 = __expf(2.f * x);
  return 1.f - 2.f * __builtin_amdgcn_rcpf(e2 + 1.f);
}

__device__ __forceinline__ void gload16(const void* g, void* l) {
  __builtin_amdgcn_global_load_lds(
      (const __attribute__((address_space(1))) unsigned int*)g,
      (__attribute__((address_space(3))) unsigned int*)l, 16, 0, 0);
}

// ---------------- prep: q2 partials (b x 8 K-slices); Wk,Wloc -> MFMA B-frag order (bf16)
__global__ __launch_bounds__(256) void prep_kernel(
    const float* __restrict__ dh, const float* __restrict__ Wq,
    const float* __restrict__ conv_b, const float* __restrict__ Wloc,
    const float* __restrict__ Wk,
    unsigned short* __restrict__ wkf, unsigned short* __restrict__ wlocf,
    float* __restrict__ q2p)
{
  int blk = blockIdx.x;
  int tid = threadIdx.x;
  if (blk < 512) {
    __shared__ float part[128];
    int b = blk >> 3, kq = blk & 7;
    int a = tid & 127, kh = tid >> 7;
    const float* dhr = dh + b * Q_ + kq * 128 + kh * 64;
    const float* wq  = Wq + (size_t)(kq * 128 + kh * 64) * A_ + a;
    float s = 0.f;
    #pragma unroll 8
    for (int k = 0; k < 64; ++k) s += dhr[k] * wq[(size_t)k * A_];
    if (kh) part[a] = s;
    __syncthreads();
    if (!kh) {
      s += part[a];
      if (kq == 0) {
        float t = 0.f;
        #pragma unroll 8
        for (int c = 0; c < C_; ++c) t += conv_b[c] * Wloc[c * A_ + a];
        s += t;
      }
      q2p[(kq * B_ + b) * A_ + a] = s;
    }
  } else if (blk < 544) {
    int wave = tid >> 6, lane = tid & 63;
    int g = (blk - 512) * 4 + wave;          // 0..127
    int ks = g >> 3, nt = g & 7;
    int lg = lane >> 4, lr = lane & 15;
    bf16x8 o;
    #pragma unroll
    for (int j = 0; j < 8; ++j)
      o[j] = f2bf(Wk[(ks * 32 + lg * 8 + j) * A_ + nt * 16 + lr]);
    *(bf16x8*)(wkf + ((size_t)g * 64 + lane) * 8) = o;
  } else {
    int wave = tid >> 6, lane = tid & 63;
    int g = (blk - 544) * 4 + wave;          // 0..7
    int lg = lane >> 4, lr = lane & 15;
    bf16x8 o;
    #pragma unroll
    for (int j = 0; j < 8; ++j)
      o[j] = f2bf(Wloc[(lg * 8 + j) * A_ + g * 16 + lr]);
    *(bf16x8*)(wlocf + ((size_t)g * 64 + lane) * 8) = o;
  }
}

// ---------------- energy: all 17 B-slices resident in LDS; zero barriers in K-loop;
// depth-2 A prefetch; launch_bounds(512,2) -> 256 VGPR budget, NO SPILLS.
__global__ __launch_bounds__(512, 2) void energy_kernel(
    const float* __restrict__ enc, const float* __restrict__ prev,
    const float* __restrict__ conv_w,
    const unsigned short* __restrict__ wkfall,   // slices 0..15 = Wk, 16 = Wloc
    const float* __restrict__ q2p, const float* __restrict__ vvec,
    float* __restrict__ outexp, float* __restrict__ psum)
{
  __shared__ unsigned short sWB[69632];   // 17 * 4096 shorts = 136 KB
  __shared__ float sprev[288];            // 256 + 30 halo
  __shared__ float scw[KW_][C_];
  __shared__ float swsum[8];

  int tid = threadIdx.x;
  int wave = tid >> 6, lane = tid & 63;
  int lg = lane >> 4, lr = lane & 15;
  int m0 = blockIdx.x * 256;              // flattened b*T + t base of this block
  int b  = m0 >> 11, t0 = m0 & (T_ - 1);
  int wm = m0 + wave * 32;                // this wave's 32 rows

  // (1) stage ALL B slices FIRST (oldest vmem ops; drained before conv compute)
  #pragma unroll
  for (int s = 0; s < 17; ++s)
    gload16(wkfall + (size_t)s * 4096 + wave * 512 + lane * 8,
            &sWB[s * 4096 + wave * 512]);

  // (2) conv inputs -> LDS
  for (int i = tid; i < 286; i += 512) {
    int t = t0 - 15 + i;
    sprev[i] = (t >= 0 && t < T_) ? prev[b * T_ + t] : 0.f;
  }
  for (int i = tid; i < KW_ * C_; i += 512)
    scw[i >> 5][i & 31] = conv_w[(i & 31) * KW_ + (i >> 5)];

  // (3) A-prefetch ks=0 (bufA) and ks=1 (bufB): 16 loads in flight
  const float* encR0 = enc + (size_t)(wm + lr) * E_ + lg * 8;
  const float* encR1 = encR0 + 16 * E_;
  float4 pa0 = *(const float4*)(encR0),      pa1 = *(const float4*)(encR0 + 4);
  float4 pa2 = *(const float4*)(encR1),      pa3 = *(const float4*)(encR1 + 4);
  float4 pb0 = *(const float4*)(encR0 + 32), pb1 = *(const float4*)(encR0 + 36);
  float4 pb2 = *(const float4*)(encR1 + 32), pb3 = *(const float4*)(encR1 + 36);

  // (4) conv compute (registers): lane owns rows (wave*32+lr, +16), ch lg*8..+8
  asm volatile("s_waitcnt lgkmcnt(0)" ::: "memory");
  __builtin_amdgcn_s_barrier();
  __builtin_amdgcn_sched_barrier(0);
  float c0[8], c1[8];
  #pragma unroll
  for (int c = 0; c < 8; ++c) { c0[c] = 0.f; c1[c] = 0.f; }
  {
    int r0 = wave * 32 + lr, r1 = r0 + 16;
    for (int j = 0; j < KW_; ++j) {
      float p0 = sprev[r0 + j], p1 = sprev[r1 + j];
      float4 wA = *(const float4*)&scw[j][lg * 8];
      float4 wB = *(const float4*)&scw[j][lg * 8 + 4];
      c0[0] += p0 * wA.x; c0[1] += p0 * wA.y; c0[2] += p0 * wA.z; c0[3] += p0 * wA.w;
      c0[4] += p0 * wB.x; c0[5] += p0 * wB.y; c0[6] += p0 * wB.z; c0[7] += p0 * wB.w;
      c1[0] += p1 * wA.x; c1[1] += p1 * wA.y; c1[2] += p1 * wA.z; c1[3] += p1 * wA.w;
      c1[4] += p1 * wB.x; c1[5] += p1 * wB.y; c1[6] += p1 * wB.z; c1[7] += p1 * wB.w;
    }
  }
  bf16x8 afl0 = pack8(make_float4(c0[0], c0[1], c0[2], c0[3]),
                      make_float4(c0[4], c0[5], c0[6], c0[7]));
  bf16x8 afl1 = pack8(make_float4(c1[0], c1[1], c1[2], c1[3]),
                      make_float4(c1[4], c1[5], c1[6], c1[7]));

  // (5) B staging complete for all waves (staging already per-wave drained;
  //     vmcnt(16) keeps the 16 A-prefetch loads in flight across the barrier)
  asm volatile("s_waitcnt vmcnt(16)" ::: "memory");
  __builtin_amdgcn_sched_barrier(0);
  __builtin_amdgcn_s_barrier();

  // (6) acc initialized with the LOCATION term (frees conv regs for the loop)
  f32x4 acc0[8], acc1[8];
  {
    const unsigned short* base = &sWB[16 * 4096 + lane * 8];
    #pragma unroll
    for (int nt = 0; nt < 8; ++nt) {
      bf16x8 bfr = *(const bf16x8*)(base + nt * 512);
      acc0[nt] = __builtin_amdgcn_mfma_f32_16x16x32_bf16(afl0, bfr, (f32x4){0,0,0,0}, 0, 0, 0);
      acc1[nt] = __builtin_amdgcn_mfma_f32_16x16x32_bf16(afl1, bfr, (f32x4){0,0,0,0}, 0, 0, 0);
    }
  }

  // (7) K-loop: depth-2 rotating prefetch, no barriers, compiler-scheduled
  #pragma unroll 1
  for (int i = 0; i < 8; ++i) {
    {
      bf16x8 af0 = pack8(pa0, pa1), af1 = pack8(pa2, pa3);
      if (i < 7) {
        const float* r0 = encR0 + (2 * i + 2) * 32;
        const float* r1 = encR1 + (2 * i + 2) * 32;
        pa0 = *(const float4*)(r0); pa1 = *(const float4*)(r0 + 4);
        pa2 = *(const float4*)(r1); pa3 = *(const float4*)(r1 + 4);
      }
      const unsigned short* base = &sWB[(2 * i) * 4096 + lane * 8];
      #pragma unroll
      for (int nt = 0; nt < 8; ++nt) {
        bf16x8 bfr = *(const bf16x8*)(base + nt * 512);
        acc0[nt] = __builtin_amdgcn_mfma_f32_16x16x32_bf16(af0, bfr, acc0[nt], 0, 0, 0);
        acc1[nt] = __builtin_amdgcn_mfma_f32_16x16x32_bf16(af1, bfr, acc1[nt], 0, 0, 0);
      }
    }
    {
      bf16x8 bg0 = pack8(pb0, pb1), bg1 = pack8(pb2, pb3);
      if (i < 7) {
        const float* r0 = encR0 + (2 * i + 3) * 32;
        const float* r1 = encR1 + (2 * i + 3) * 32;
        pb0 = *(const float4*)(r0); pb1 = *(const float4*)(r0 + 4);
        pb2 = *(const float4*)(r1); pb3 = *(const float4*)(r1 + 4);
      }
      const unsigned short* base = &sWB[(2 * i + 1) * 4096 + lane * 8];
      #pragma unroll
      for (int nt = 0; nt < 8; ++nt) {
        bf16x8 bfr = *(const bf16x8*)(base + nt * 512);
        acc0[nt] = __builtin_amdgcn_mfma_f32_16x16x32_bf16(bg0, bfr, acc0[nt], 0, 0, 0);
        acc1[nt] = __builtin_amdgcn_mfma_f32_16x16x32_bf16(bg1, bfr, acc1[nt], 0, 0, 0);
      }
    }
  }

  // (8) epilogue: qv = sum of 8 q2 partials; p = v.tanh(acc+qv); out = exp(p)
  float qv[8], vv[8];
  #pragma unroll
  for (int nt = 0; nt < 8; ++nt) {
    int n = nt * 16 + lr;
    float s = 0.f;
    #pragma unroll
    for (int p = 0; p < 8; ++p) s += q2p[(p * B_ + b) * A_ + n];
    qv[nt] = s;
    vv[nt] = vvec[n];
  }
  float ssum = 0.f;
  #pragma unroll
  for (int f = 0; f < 2; ++f) {
    f32x4* acc = f ? acc1 : acc0;
    float p0 = 0, p1 = 0, p2 = 0, p3 = 0;
    #pragma unroll
    for (int nt = 0; nt < 8; ++nt) {
      p0 += fast_tanh(acc[nt][0] + qv[nt]) * vv[nt];
      p1 += fast_tanh(acc[nt][1] + qv[nt]) * vv[nt];
      p2 += fast_tanh(acc[nt][2] + qv[nt]) * vv[nt];
      p3 += fast_tanh(acc[nt][3] + qv[nt]) * vv[nt];
    }
    #pragma unroll
    for (int off = 1; off < 16; off <<= 1) {
      p0 += __shfl_xor(p0, off, 64);
      p1 += __shfl_xor(p1, off, 64);
      p2 += __shfl_xor(p2, off, 64);
      p3 += __shfl_xor(p3, off, 64);
    }
    float e0 = __expf(p0), e1 = __expf(p1), e2 = __expf(p2), e3 = __expf(p3);
    ssum += (e0 + e1) + (e2 + e3);
    if (lr == 0)
      *(float4*)(outexp + wm + f * 16 + lg * 4) = make_float4(e0, e1, e2, e3);
  }
  ssum += __shfl_xor(ssum, 16, 64);
  ssum += __shfl_xor(ssum, 32, 64);
  if (lane == 0) swsum[wave] = ssum;
  __syncthreads();
  if (tid == 0) {
    float s = 0.f;
    #pragma unroll
    for (int wv = 0; wv < 8; ++wv) s += swsum[wv];
    psum[b * 8 + (blockIdx.x & 7)] = s;
  }
}

// ---------------- normalize: out[b,:] *= 1/sum(psum[b,:])
__global__ __launch_bounds__(256) void norm_kernel(float* __restrict__ out,
                                                   const float* __restrict__ psum)
{
  int b = blockIdx.x, tid = threadIdx.x;
  float s = 0.f;
  #pragma unroll
  for (int p = 0; p < 8; ++p) s += psum[b * 8 + p];
  float inv = 1.f / s;
  float4* row = (float4*)(out + (size_t)b * T_);
  #pragma unroll
  for (int j = 0; j < 2; ++j) {
    float4 x = row[tid + j * 256];
    x.x *= inv; x.y *= inv; x.z *= inv; x.w *= inv;
    row[tid + j * 256] = x;
  }
}

extern "C" void kernel_launch(void* const* d_in, const int* in_sizes, int n_in,
                              void* d_out, int out_size, void* d_ws, size_t ws_size,
                              hipStream_t stream)
{
  const float* enc   = (const float*)d_in[0];
  const float* dh    = (const float*)d_in[1];
  const float* prev  = (const float*)d_in[2];
  const float* Wq    = (const float*)d_in[3];
  const float* Wk    = (const float*)d_in[4];
  const float* convw = (const float*)d_in[5];
  const float* convb = (const float*)d_in[6];
  const float* Wloc  = (const float*)d_in[7];
  const float* v     = (const float*)d_in[8];
  float* out = (float*)d_out;

  char* w = (char*)d_ws;
  unsigned short* wkf   = (unsigned short*)w;               // slices 0..15, 131072 B
  unsigned short* wlocf = (unsigned short*)(w + 131072);    // slice 16, 8192 B (contiguous)
  float*          q2p   = (float*)(w + 139264);             // 8*64*128 f32 = 262144 B
  float*          psum  = (float*)(w + 401408);             // 64*8 f32 = 2048 B

  hipLaunchKernelGGL(prep_kernel, dim3(546), dim3(256), 0, stream,
                     dh, Wq, convb, Wloc, Wk, wkf, wlocf, q2p);
  hipLaunchKernelGGL(energy_kernel, dim3(512), dim3(512), 0, stream,
                     enc, prev, convw, wkf, q2p, v, out, psum);
  hipLaunchKernelGGL(norm_kernel, dim3(64), dim3(256), 0, stream, out, psum);
}